// Round 14
// baseline (180.435 us; speedup 1.0000x reference)
//
#include <hip/hip_runtime.h>

typedef __bf16 bf16v8 __attribute__((ext_vector_type(8)));
typedef float f32x4 __attribute__((ext_vector_type(4)));

#define AS1 __attribute__((address_space(1)))
#define AS3 __attribute__((address_space(3)))

__device__ __forceinline__ void gl_lds16(const void* g, void* s) {
  __builtin_amdgcn_global_load_lds((const AS1 void*)g, (AS3 void*)s, 16, 0, 0);
}

__device__ __forceinline__ unsigned short f2b(float f) {
  union { float f; unsigned u; } v; v.f = f;
  unsigned r = v.u + 0x7fffu + ((v.u >> 16) & 1u);
  return (unsigned short)(r >> 16);
}

__device__ __forceinline__ float bitsf(unsigned u) {
  union { unsigned u; float f; } v; v.u = u;
  return v.f;
}

// ---------------- fused fp32 -> bf16 convert (x, wq, w1, w2 in one launch) ----------------
__global__ __launch_bounds__(256) void cvt_all(const float* __restrict__ x,
                                               const float* __restrict__ wq,
                                               const float* __restrict__ w1,
                                               const float* __restrict__ w2,
                                               unsigned short* __restrict__ xb,
                                               unsigned short* __restrict__ wqb,
                                               unsigned short* __restrict__ w1b,
                                               unsigned short* __restrict__ w2b) {
  int bid = blockIdx.x;
  const float* in;
  unsigned short* out;
  int base;
  if (bid < 4096)       { in = x;  out = xb;  base = bid; }
  else if (bid < 5120)  { in = wq; out = wqb; base = bid - 4096; }
  else if (bid < 9216)  { in = w1; out = w1b; base = bid - 5120; }
  else                  { in = w2; out = w2b; base = bid - 9216; }
  long i = ((long)base * 256 + threadIdx.x) * 4;
  float4 v = *(const float4*)(in + i);
  ushort4 u = make_ushort4(f2b(v.x), f2b(v.y), f2b(v.z), f2b(v.w));
  *(ushort4*)(out + i) = u;
}

// ============ 256x128 bf16 GEMM, BK=32, 8 waves (4Mx2N), 48 KB LDS, 2 blocks/CU ============
// Simple 2-phase: stage(next) -> frag reads -> MFMA -> syncthreads. Cross-block overlap
// (2 co-resident blocks/CU) hides the barrier drain (m97/m114 mechanism).
// A [M,K], B [N,K] row-major bf16; C[m][n] = sum_k A.B (+bias,+relu). Ks mult of 32.
template <int RELU, int SPLIT>
__global__ __launch_bounds__(512, 2) void gemm_bn(const unsigned short* __restrict__ A,
                                                  const unsigned short* __restrict__ B,
                                                  const float* __restrict__ bias,
                                                  unsigned short* __restrict__ Cb,
                                                  int M, int N, int K, int Ks) {
  __shared__ unsigned short As[2][256 * 32];  // 32 KB
  __shared__ unsigned short Bs[2][128 * 32];  // 16 KB

  const int tid = threadIdx.x;
  const int wave = tid >> 6, lane = tid & 63;
  const int wr = wave >> 1, wc = wave & 1;   // 4 x 2 wave grid, 64x64 out per wave
  const int g = lane >> 4, l15 = lane & 15;

  // XCD-aware bijective block swizzle (nwg % 8 == 0 for all our grids)
  const int gx = gridDim.x;
  const int nwg = gx * gridDim.y;
  const int lin = blockIdx.y * gx + blockIdx.x;
  const int cpx = nwg >> 3;
  const int swz = (lin & 7) * cpx + (lin >> 3);
  const long m0 = (long)(swz / gx) * 256;
  const long n0 = (long)(swz % gx) * 128;
  const int kBase = blockIdx.z * Ks;

  // staging (gl_lds: uniform LDS base + lane*16). chunk-slot idx -> row=idx>>2, p=idx&3;
  // source column pre-swizzled: data chunk p^((row>>1)&3) lands at LDS chunk p.
  auto stage = [&](int buf, int kb) {
#pragma unroll
    for (int j = 0; j < 2; ++j) {   // A: 1024 slots = 2 rounds of 512
      int idx = (j * 8 + wave) * 64 + lane;
      int row = idx >> 2, p = idx & 3;
      gl_lds16(A + (m0 + row) * (long)K + kb + ((p ^ ((row >> 1) & 3)) << 3),
               &As[buf][(j * 8 + wave) * 512]);
    }
    {                                // B: 512 slots = 1 round
      int idx = wave * 64 + lane;
      int row = idx >> 2, p = idx & 3;
      gl_lds16(B + (n0 + row) * (long)K + kb + ((p ^ ((row >> 1) & 3)) << 3),
               &Bs[buf][wave * 512]);
    }
  };

  f32x4 acc[4][4] = {};
  const int nt = Ks >> 5;

  stage(0, kBase);
  __syncthreads();

  int cur = 0;
  for (int t = 0; t < nt; ++t) {
    if (t + 1 < nt) stage(cur ^ 1, kBase + ((t + 1) << 5));

    bf16v8 af[4], bn[4];
#pragma unroll
    for (int m = 0; m < 4; ++m) {
      int row = wr * 64 + m * 16 + l15;
      af[m] = *(const bf16v8*)&As[cur][row * 32 + ((g ^ ((row >> 1) & 3)) << 3)];
    }
#pragma unroll
    for (int n = 0; n < 4; ++n) {
      int row = wc * 64 + n * 16 + l15;
      bn[n] = *(const bf16v8*)&Bs[cur][row * 32 + ((g ^ ((row >> 1) & 3)) << 3)];
    }
    __builtin_amdgcn_s_setprio(1);
#pragma unroll
    for (int m = 0; m < 4; ++m)
#pragma unroll
      for (int n = 0; n < 4; ++n)
        acc[m][n] = __builtin_amdgcn_mfma_f32_16x16x32_bf16(af[m], bn[n], acc[m][n], 0, 0, 0);
    __builtin_amdgcn_s_setprio(0);
    __syncthreads();
    cur ^= 1;
  }

  const long zoff = SPLIT ? (long)blockIdx.z * M * (long)N : 0;
#pragma unroll
  for (int m = 0; m < 4; ++m)
#pragma unroll
    for (int n = 0; n < 4; ++n) {
      long col = n0 + wc * 64 + n * 16 + l15;
      float bv = SPLIT ? 0.f : bias[col];
      long rowb = m0 + wr * 64 + m * 16 + g * 4;
#pragma unroll
      for (int i = 0; i < 4; ++i) {
        float v = acc[m][n][i] + bv;
        if (RELU) v = fmaxf(v, 0.f);
        Cb[zoff + (rowb + i) * (long)N + col] = f2b(v);
      }
    }
}

// ---------------- merge four bf16 split-K partials + bias -> bf16 ----------------
__global__ __launch_bounds__(256) void merge4_bias(const unsigned short* __restrict__ p,
                                                   const float* __restrict__ bias,
                                                   unsigned short* __restrict__ out) {
  const long PS = 4096L * 1024L;
  long i = ((long)blockIdx.x * 256 + threadIdx.x) * 8;
  int col = (int)(i & 1023);
  float4 b0 = *(const float4*)(bias + col);
  float4 b1 = *(const float4*)(bias + col + 4);
  float acc[8] = {b0.x, b0.y, b0.z, b0.w, b1.x, b1.y, b1.z, b1.w};
#pragma unroll
  for (int sp = 0; sp < 4; ++sp) {
    uint4 u = *(const uint4*)(p + sp * PS + i);
    unsigned r[4] = {u.x, u.y, u.z, u.w};
#pragma unroll
    for (int j = 0; j < 4; ++j) {
      acc[j * 2]     += bitsf(r[j] << 16);
      acc[j * 2 + 1] += bitsf(r[j] & 0xffff0000u);
    }
  }
  unsigned short res[8];
#pragma unroll
  for (int j = 0; j < 8; ++j) res[j] = f2b(acc[j]);
  *(uint4*)(out + i) = *(uint4*)res;
}

// ---------------- flash attention v6: QBLK=256, intra-block split-KV, in-register P ----------------
__global__ __launch_bounds__(512, 2) void attn_kernel(const unsigned short* __restrict__ h,
                                                      unsigned short* __restrict__ o) {
  const int id = blockIdx.y * 8 + blockIdx.x;   // grid (8,32) = 256 blocks
  const int bh = id & 31;
  const int b = bh >> 4, head = bh & 15;
  const int q0 = (id >> 5) * 256;
  const unsigned short* hb = h + (long)b * 2048 * 1024 + head * 64;

  __shared__ unsigned short smem[2 * 19712];

  const int tid = threadIdx.x, wave = tid >> 6, lane = tid & 63;
  const int grp = wave >> 2, wg = wave & 3;
  const int g = lane >> 4, l15 = lane & 15;
  const int vcb = wg * 16;
  unsigned short* Ks0 = smem + grp * 19712;
  unsigned short* VTb = Ks0 + 8192;

  for (int idx = wg * 64 + lane; idx < 16 * 72; idx += 256) {
    unsigned short v = (idx < 72) ? (unsigned short)0x3F80 : (unsigned short)0;
    VTb[64 * 72 + idx] = v;
    VTb[5760 + 64 * 72 + idx] = v;
  }

  const float C1 = 0.18033688011112042f;  // 0.125 * log2(e)

  bf16v8 qf[4][2];
#pragma unroll
  for (int qt = 0; qt < 4; ++qt)
#pragma unroll
    for (int d = 0; d < 2; ++d) {
      bf16v8 q = *(const bf16v8*)(hb + (long)(q0 + wg * 64 + qt * 16 + l15) * 1024 + d * 32 + g * 8);
#pragma unroll
      for (int j = 0; j < 8; ++j) q[j] = (__bf16)((float)q[j] * C1);
      qf[qt][d] = q;
    }

  const int krow = lane >> 3;
  const int kcol = ((lane & 7) ^ (krow & 7)) << 3;

  const int kl = lane;
  const int vpos = ((kl >> 5) << 5) + (((kl & 15) >> 2) << 3) + (((kl >> 4) & 1) << 2) + (kl & 3);

#pragma unroll
  for (int s = 0; s < 2; ++s) {
    int seg = wg * 2 + s;
    gl_lds16(hb + (long)(grp * 64 + seg * 8 + krow) * 1024 + kcol, Ks0 + seg * 512);
  }
  uint4 va0, va1;
  {
    const unsigned short* vg = hb + (long)(grp * 64 + lane) * 1024 + vcb;
    va0 = *(const uint4*)vg;
    va1 = *(const uint4*)(vg + 8);
  }
  {
    unsigned short vv[16];
    *(uint4*)&vv[0] = va0;
    *(uint4*)&vv[8] = va1;
#pragma unroll
    for (int j = 0; j < 16; ++j) VTb[(vcb + j) * 72 + vpos] = vv[j];
  }
  __syncthreads();

  f32x4 accO[4][4] = {};
  f32x4 accL[4] = {};

  int cur = 0;
  for (int t = 0; t < 16; ++t) {
    if (t < 15) {
      const int k0n = ((t + 1) * 2 + grp) * 64;
#pragma unroll
      for (int s = 0; s < 2; ++s) {
        int seg = wg * 2 + s;
        gl_lds16(hb + (long)(k0n + seg * 8 + krow) * 1024 + kcol, Ks0 + (cur ^ 1) * 4096 + seg * 512);
      }
      const unsigned short* vg = hb + (long)(k0n + lane) * 1024 + vcb;
      va0 = *(const uint4*)vg;
      va1 = *(const uint4*)(vg + 8);
    }

    const unsigned short* Kc = Ks0 + cur * 4096;
    f32x4 sf[4][4] = {};
#pragma unroll
    for (int d = 0; d < 2; ++d) {
#pragma unroll
      for (int kt = 0; kt < 4; ++kt) {
        int r = kt * 16 + l15;
        bf16v8 kf = *(const bf16v8*)&Kc[r * 64 + ((((d << 2) + g) ^ (r & 7)) << 3)];
#pragma unroll
        for (int qt = 0; qt < 4; ++qt)
          sf[kt][qt] = __builtin_amdgcn_mfma_f32_16x16x32_bf16(kf, qf[qt][d], sf[kt][qt], 0, 0, 0);
      }
    }

    bf16v8 pa[4][2];
#pragma unroll
    for (int qt = 0; qt < 4; ++qt) {
      float pe[4][4];
#pragma unroll
      for (int kt = 0; kt < 4; ++kt)
#pragma unroll
        for (int i = 0; i < 4; ++i)
          pe[kt][i] = __builtin_amdgcn_exp2f(sf[kt][qt][i]);
#pragma unroll
      for (int i = 0; i < 4; ++i) {
        pa[qt][0][i]     = (__bf16)pe[0][i];
        pa[qt][0][i + 4] = (__bf16)pe[1][i];
        pa[qt][1][i]     = (__bf16)pe[2][i];
        pa[qt][1][i + 4] = (__bf16)pe[3][i];
      }
    }

    const unsigned short* VTc = VTb + cur * 5760;
#pragma unroll
    for (int ks = 0; ks < 2; ++ks) {
      bf16v8 vl = *(const bf16v8*)&VTc[(64 + l15) * 72 + ks * 32 + g * 8];
#pragma unroll
      for (int dt = 0; dt < 4; ++dt) {
        bf16v8 vf = *(const bf16v8*)&VTc[(dt * 16 + l15) * 72 + ks * 32 + g * 8];
#pragma unroll
        for (int qt = 0; qt < 4; ++qt)
          accO[qt][dt] = __builtin_amdgcn_mfma_f32_16x16x32_bf16(pa[qt][ks], vf, accO[qt][dt], 0, 0, 0);
      }
#pragma unroll
      for (int qt = 0; qt < 4; ++qt)
        accL[qt] = __builtin_amdgcn_mfma_f32_16x16x32_bf16(pa[qt][ks], vl, accL[qt], 0, 0, 0);
    }

    if (t < 15) {
      unsigned short vv[16];
      *(uint4*)&vv[0] = va0;
      *(uint4*)&vv[8] = va1;
      unsigned short* VTn = VTb + (cur ^ 1) * 5760;
#pragma unroll
      for (int j = 0; j < 16; ++j) VTn[(vcb + j) * 72 + vpos] = vv[j];
    }
    __syncthreads();
    cur ^= 1;
  }

  float* redO = (float*)smem;
  float* redL = (float*)smem + 16384;
  if (grp == 1) {
#pragma unroll
    for (int qt = 0; qt < 4; ++qt)
#pragma unroll
      for (int i = 0; i < 4; ++i) {
        int r = wg * 64 + qt * 16 + g * 4 + i;
#pragma unroll
        for (int dt = 0; dt < 4; ++dt)
          redO[r * 64 + dt * 16 + l15] = accO[qt][dt][i];
        if (l15 == 0) redL[r] = accL[qt][i];
      }
  }
  __syncthreads();
  if (grp == 0) {
#pragma unroll
    for (int qt = 0; qt < 4; ++qt)
#pragma unroll
      for (int i = 0; i < 4; ++i) {
        int r = wg * 64 + qt * 16 + g * 4 + i;
#pragma unroll
        for (int dt = 0; dt < 4; ++dt)
          accO[qt][dt][i] += redO[r * 64 + dt * 16 + l15];
        accL[qt][i] += redL[r];
      }
#pragma unroll
    for (int qt = 0; qt < 4; ++qt)
#pragma unroll
      for (int i = 0; i < 4; ++i) {
        float linv = 1.f / __shfl(accL[qt][i], lane & 48);
        long row = (long)b * 2048 + q0 + wg * 64 + qt * 16 + g * 4 + i;
#pragma unroll
        for (int dt = 0; dt < 4; ++dt)
          o[row * 1024 + head * 64 + dt * 16 + l15] = f2b(accO[qt][dt][i] * linv);
      }
  }
}

// ---------------- LN1: out = LN(x + att_bf16); writes f32 + bf16 ----------------
__global__ __launch_bounds__(256) void ln1_attb(const float* __restrict__ xa,
                                                const unsigned short* __restrict__ ab,
                                                const float* __restrict__ g,
                                                const float* __restrict__ be,
                                                float* __restrict__ of,
                                                unsigned short* __restrict__ ob) {
  const long base = (long)blockIdx.x * 1024;
  const int t = threadIdx.x;
  float4 va = *(const float4*)(xa + base + t * 4);
  uint2 ub = *(const uint2*)(ab + base + t * 4);
  float v0 = va.x + bitsf(ub.x << 16);
  float v1 = va.y + bitsf(ub.x & 0xffff0000u);
  float v2 = va.z + bitsf(ub.y << 16);
  float v3 = va.w + bitsf(ub.y & 0xffff0000u);
  float s = v0 + v1 + v2 + v3;
  float sq = v0 * v0 + v1 * v1 + v2 * v2 + v3 * v3;
#pragma unroll
  for (int m = 1; m < 64; m <<= 1) { s += __shfl_xor(s, m); sq += __shfl_xor(sq, m); }
  __shared__ float red[8];
  const int wave = t >> 6, lane = t & 63;
  if (lane == 0) { red[wave] = s; red[4 + wave] = sq; }
  __syncthreads();
  s = red[0] + red[1] + red[2] + red[3];
  sq = red[4] + red[5] + red[6] + red[7];
  float mean = s * (1.f / 1024.f);
  float var = fmaxf(sq - s * mean, 0.f) * (1.f / 1023.f);
  float inv = 1.f / (sqrtf(var) + 1e-6f);
  float4 gg = *(const float4*)(g + t * 4);
  float4 bb = *(const float4*)(be + t * 4);
  float y0 = gg.x * ((v0 - mean) * inv) + bb.x;
  float y1 = gg.y * ((v1 - mean) * inv) + bb.y;
  float y2 = gg.z * ((v2 - mean) * inv) + bb.z;
  float y3 = gg.w * ((v3 - mean) * inv) + bb.w;
  *(float4*)(of + base + t * 4) = make_float4(y0, y1, y2, y3);
  ushort4 u = make_ushort4(f2b(y0), f2b(y1), f2b(y2), f2b(y3));
  *(ushort4*)(ob + base + t * 4) = u;
}

// ---------------- LN2: out = LN(x1 + sum_4 zp[s] + b2) ----------------
__global__ __launch_bounds__(256) void ln_add_red4(const float* __restrict__ xa,
                                                   const unsigned short* __restrict__ zp,
                                                   const float* __restrict__ bias,
                                                   const float* __restrict__ g,
                                                   const float* __restrict__ be,
                                                   float* __restrict__ of) {
  const long base = (long)blockIdx.x * 1024;
  const int t = threadIdx.x;
  const long PS = 4096L * 1024L;
  float4 va = *(const float4*)(xa + base + t * 4);
  float4 bz = *(const float4*)(bias + t * 4);
  float v0 = va.x + bz.x, v1 = va.y + bz.y, v2 = va.z + bz.z, v3 = va.w + bz.w;
#pragma unroll
  for (int sp = 0; sp < 4; ++sp) {
    uint2 u = *(const uint2*)(zp + sp * PS + base + t * 4);
    v0 += bitsf(u.x << 16);
    v1 += bitsf(u.x & 0xffff0000u);
    v2 += bitsf(u.y << 16);
    v3 += bitsf(u.y & 0xffff0000u);
  }
  float s = v0 + v1 + v2 + v3;
  float sq = v0 * v0 + v1 * v1 + v2 * v2 + v3 * v3;
#pragma unroll
  for (int m = 1; m < 64; m <<= 1) { s += __shfl_xor(s, m); sq += __shfl_xor(sq, m); }
  __shared__ float red[8];
  const int wave = t >> 6, lane = t & 63;
  if (lane == 0) { red[wave] = s; red[4 + wave] = sq; }
  __syncthreads();
  s = red[0] + red[1] + red[2] + red[3];
  sq = red[4] + red[5] + red[6] + red[7];
  float mean = s * (1.f / 1024.f);
  float var = fmaxf(sq - s * mean, 0.f) * (1.f / 1023.f);
  float inv = 1.f / (sqrtf(var) + 1e-6f);
  float4 gg = *(const float4*)(g + t * 4);
  float4 bb = *(const float4*)(be + t * 4);
  float y0 = gg.x * ((v0 - mean) * inv) + bb.x;
  float y1 = gg.y * ((v1 - mean) * inv) + bb.y;
  float y2 = gg.z * ((v2 - mean) * inv) + bb.z;
  float y3 = gg.w * ((v3 - mean) * inv) + bb.w;
  *(float4*)(of + base + t * 4) = make_float4(y0, y1, y2, y3);
}

extern "C" void kernel_launch(void* const* d_in, const int* in_sizes, int n_in,
                              void* d_out, int out_size, void* d_ws, size_t ws_size,
                              hipStream_t stream) {
  const float* x    = (const float*)d_in[0];
  const float* wq   = (const float*)d_in[1];
  const float* bq   = (const float*)d_in[2];
  const float* ln1a = (const float*)d_in[3];
  const float* ln1b = (const float*)d_in[4];
  const float* ln2a = (const float*)d_in[5];
  const float* ln2b = (const float*)d_in[6];
  const float* w1   = (const float*)d_in[7];
  const float* b1   = (const float*)d_in[8];
  const float* w2   = (const float*)d_in[9];
  const float* b2   = (const float*)d_in[10];
  float* out = (float*)d_out;

  char* ws = (char*)d_ws;
  const size_t MB = 1024 * 1024;
  unsigned short* xb  = (unsigned short*)(ws);            // [0,8)
  unsigned short* wqb = (unsigned short*)(ws + 8 * MB);   // [8,10)
  unsigned short* w1b = (unsigned short*)(ws + 10 * MB);  // [10,18)
  unsigned short* w2b = (unsigned short*)(ws + 18 * MB);  // [18,26)
  unsigned short* qp  = (unsigned short*)(ws + 26 * MB);  // [26,58) QKV partials
  unsigned short* yb  = (unsigned short*)(ws + 26 * MB);  // [26,58) FFN mid (after ln1)
  unsigned short* hb  = (unsigned short*)(ws + 58 * MB);  // [58,66)
  unsigned short* att = (unsigned short*)(ws + 66 * MB);  // [66,74) bf16
  unsigned short* zp  = (unsigned short*)(ws + 58 * MB);  // [58,90) FFN2 partials
  float*          x1f = (float*)(ws + 90 * MB);           // [90,106)
  unsigned short* x1b = (unsigned short*)(ws + 106 * MB); // [106,114)

  // all fp32->bf16 converts in one launch
  cvt_all<<<13312, 256, 0, stream>>>(x, wq, w1, w2, xb, wqb, w1b, w2b);

  // h partials = x @ wq^T (split-K=4), merge + bq -> hb
  gemm_bn<0, 1><<<dim3(8, 16, 4), 512, 0, stream>>>(xb, wqb, nullptr, qp,
                                                    4096, 1024, 1024, 256);
  merge4_bias<<<2048, 256, 0, stream>>>(qp, bq, hb);

  // attention (QBLK=256, intra-block split-KV, 512 threads; bf16 out)
  attn_kernel<<<dim3(8, 32), 512, 0, stream>>>(hb, att);

  // x1 = LN(x + att)
  ln1_attb<<<4096, 256, 0, stream>>>(x, att, ln1a, ln1b, x1f, x1b);

  // y = relu(x1 @ w1^T + b1)
  gemm_bn<1, 0><<<dim3(32, 16, 1), 512, 0, stream>>>(x1b, w1b, b1, yb,
                                                     4096, 4096, 1024, 1024);

  // z partials = y @ w2^T (split-K=4; b2 added in LN2)
  gemm_bn<0, 1><<<dim3(8, 16, 4), 512, 0, stream>>>(yb, w2b, nullptr, zp,
                                                    4096, 1024, 4096, 1024);

  // out = LN(x1 + sum(zp) + b2)
  ln_add_red4<<<4096, 256, 0, stream>>>(x1f, zp, b2, ln2a, ln2b, out);
}

// Round 15
// 177.395 us; speedup vs baseline: 1.0171x; 1.0171x over previous
//
#include <hip/hip_runtime.h>

typedef __bf16 bf16v8 __attribute__((ext_vector_type(8)));
typedef float f32x4 __attribute__((ext_vector_type(4)));

#define AS1 __attribute__((address_space(1)))
#define AS3 __attribute__((address_space(3)))

__device__ __forceinline__ void gl_lds16(const void* g, void* s) {
  __builtin_amdgcn_global_load_lds((const AS1 void*)g, (AS3 void*)s, 16, 0, 0);
}

__device__ __forceinline__ unsigned short f2b(float f) {
  union { float f; unsigned u; } v; v.f = f;
  unsigned r = v.u + 0x7fffu + ((v.u >> 16) & 1u);
  return (unsigned short)(r >> 16);
}

__device__ __forceinline__ float bitsf(unsigned u) {
  union { unsigned u; float f; } v; v.u = u;
  return v.f;
}

// ---------------- fused fp32 -> bf16 convert (x, wq, w1, w2 in one launch) ----------------
__global__ __launch_bounds__(256) void cvt_all(const float* __restrict__ x,
                                               const float* __restrict__ wq,
                                               const float* __restrict__ w1,
                                               const float* __restrict__ w2,
                                               unsigned short* __restrict__ xb,
                                               unsigned short* __restrict__ wqb,
                                               unsigned short* __restrict__ w1b,
                                               unsigned short* __restrict__ w2b) {
  int bid = blockIdx.x;
  const float* in;
  unsigned short* out;
  int base;
  if (bid < 4096)       { in = x;  out = xb;  base = bid; }
  else if (bid < 5120)  { in = wq; out = wqb; base = bid - 4096; }
  else if (bid < 9216)  { in = w1; out = w1b; base = bid - 5120; }
  else                  { in = w2; out = w2b; base = bid - 9216; }
  long i = ((long)base * 256 + threadIdx.x) * 4;
  float4 v = *(const float4*)(in + i);
  ushort4 u = make_ushort4(f2b(v.x), f2b(v.y), f2b(v.z), f2b(v.w));
  *(ushort4*)(out + i) = u;
}

// ============ 256x256 bf16 GEMM, 8 waves, 4-phase counted-vmcnt, EVEN read bursts ============
// Phases: P1 reads b0-3(k0)+af0-3(k0) [8], P2 reads af4-7(k0) [4, B held in regs],
// P3/P4 mirror for k1. Staging (A-k0, B-k0, A-k1, B-k1 of next tile, one unit/phase)
// and vmcnt(4) ledger identical to the round-11-verified schedule.
template <int RELU, int SPLIT>
__global__ __launch_bounds__(512, 2) void gemm256p(const unsigned short* __restrict__ A,
                                                   const unsigned short* __restrict__ B,
                                                   const float* __restrict__ bias,
                                                   unsigned short* __restrict__ Cb,
                                                   int M, int N, int K, int Ks) {
  __shared__ unsigned short As[2][2][8192];  // [buf][kk][256*32] = 64 KB
  __shared__ unsigned short Bs[2][2][8192];  // 64 KB

  const int tid = threadIdx.x;
  const int wave = tid >> 6, lane = tid & 63;
  const int wr = wave >> 2, wc = wave & 3;       // 2 x 4 wave grid
  const int g = lane >> 4, l15 = lane & 15;

  // XCD-aware bijective block swizzle (nwg % 8 == 0 for all our grids)
  const int gx = gridDim.x;
  const int nwg = gx * gridDim.y;
  const int lin = blockIdx.y * gx + blockIdx.x;
  const int cpx = nwg >> 3;
  const int swz = (lin & 7) * cpx + (lin >> 3);
  const long m0 = (long)(swz / gx) * 256;
  const long n0 = (long)(swz % gx) * 256;
  const int kBase = blockIdx.z * Ks;

  // staging: lane covers row seg*16 + (lane>>2), source 16B-chunk (lane&3)^((row>>1)&3)
  const int srow = lane >> 2;
  const int schunk = ((lane & 3) ^ ((lane >> 3) & 3)) * 8;

  auto stA = [&](int buf, int kk, int kb) {
#pragma unroll
    for (int j = 0; j < 2; ++j) {
      const int seg = wave * 2 + j;
      gl_lds16(A + (m0 + seg * 16 + srow) * (long)K + kb + kk * 32 + schunk,
               &As[buf][kk][seg * 512]);
    }
  };
  auto stB = [&](int buf, int kk, int kb) {
#pragma unroll
    for (int j = 0; j < 2; ++j) {
      const int seg = wave * 2 + j;
      gl_lds16(B + (n0 + seg * 16 + srow) * (long)K + kb + kk * 32 + schunk,
               &Bs[buf][kk][seg * 512]);
    }
  };

  // swizzled fragment read column (per-lane constant)
  const int sel = (l15 >> 1) & 3;
  const int colA = (g ^ sel) << 3;

  f32x4 acc[8][4] = {};
  const int nt = Ks >> 6;

  // prologue: stage tile 0 (A-k0, B-k0, A-k1, B-k1); publish [0][0]
  stA(0, 0, kBase); stB(0, 0, kBase); stA(0, 1, kBase); stB(0, 1, kBase);
  asm volatile("s_waitcnt vmcnt(4)" ::: "memory");
  __builtin_amdgcn_s_barrier();

  int cur = 0;
  for (int t = 0; t < nt; ++t) {
    const bool pf = (t + 1 < nt);
    const int kbn = kBase + ((t + 1) << 6);
    bf16v8 af[4], bn[4];

    // ---- P1: reads [cur][0] bn0-3 + af(m0-3) ; stage A(next,0)
#pragma unroll
    for (int n = 0; n < 4; ++n)
      bn[n] = *(const bf16v8*)&Bs[cur][0][(wc * 64 + n * 16 + l15) * 32 + colA];
#pragma unroll
    for (int m = 0; m < 4; ++m)
      af[m] = *(const bf16v8*)&As[cur][0][(wr * 128 + m * 16 + l15) * 32 + colA];
    if (pf) stA(cur ^ 1, 0, kbn);
    __builtin_amdgcn_s_barrier();
    asm volatile("s_waitcnt lgkmcnt(0)" ::: "memory");
    __builtin_amdgcn_s_setprio(1);
#pragma unroll
    for (int m = 0; m < 4; ++m)
#pragma unroll
      for (int n = 0; n < 4; ++n)
        acc[m][n] = __builtin_amdgcn_mfma_f32_16x16x32_bf16(af[m], bn[n], acc[m][n], 0, 0, 0);
    __builtin_amdgcn_s_setprio(0);
    __builtin_amdgcn_s_barrier();

    // ---- P2: reads [cur][0] af(m4-7) ; stage B(next,0) ; publish [cur][1]
#pragma unroll
    for (int m = 0; m < 4; ++m)
      af[m] = *(const bf16v8*)&As[cur][0][(wr * 128 + (m + 4) * 16 + l15) * 32 + colA];
    if (pf) stB(cur ^ 1, 0, kbn);
    __builtin_amdgcn_s_barrier();
    asm volatile("s_waitcnt lgkmcnt(0)" ::: "memory");
    __builtin_amdgcn_s_setprio(1);
#pragma unroll
    for (int m = 0; m < 4; ++m)
#pragma unroll
      for (int n = 0; n < 4; ++n)
        acc[m + 4][n] = __builtin_amdgcn_mfma_f32_16x16x32_bf16(af[m], bn[n], acc[m + 4][n], 0, 0, 0);
    __builtin_amdgcn_s_setprio(0);
    if (pf) { asm volatile("s_waitcnt vmcnt(4)" ::: "memory"); }
    else    { asm volatile("s_waitcnt vmcnt(0)" ::: "memory"); }
    __builtin_amdgcn_s_barrier();

    // ---- P3: reads [cur][1] bn0-3 + af(m0-3) ; stage A(next,1)
#pragma unroll
    for (int n = 0; n < 4; ++n)
      bn[n] = *(const bf16v8*)&Bs[cur][1][(wc * 64 + n * 16 + l15) * 32 + colA];
#pragma unroll
    for (int m = 0; m < 4; ++m)
      af[m] = *(const bf16v8*)&As[cur][1][(wr * 128 + m * 16 + l15) * 32 + colA];
    if (pf) stA(cur ^ 1, 1, kbn);
    __builtin_amdgcn_s_barrier();
    asm volatile("s_waitcnt lgkmcnt(0)" ::: "memory");
    __builtin_amdgcn_s_setprio(1);
#pragma unroll
    for (int m = 0; m < 4; ++m)
#pragma unroll
      for (int n = 0; n < 4; ++n)
        acc[m][n] = __builtin_amdgcn_mfma_f32_16x16x32_bf16(af[m], bn[n], acc[m][n], 0, 0, 0);
    __builtin_amdgcn_s_setprio(0);
    __builtin_amdgcn_s_barrier();

    // ---- P4: reads [cur][1] af(m4-7) ; stage B(next,1) ; publish [next][0]
#pragma unroll
    for (int m = 0; m < 4; ++m)
      af[m] = *(const bf16v8*)&As[cur][1][(wr * 128 + (m + 4) * 16 + l15) * 32 + colA];
    if (pf) stB(cur ^ 1, 1, kbn);
    __builtin_amdgcn_s_barrier();
    asm volatile("s_waitcnt lgkmcnt(0)" ::: "memory");
    __builtin_amdgcn_s_setprio(1);
#pragma unroll
    for (int m = 0; m < 4; ++m)
#pragma unroll
      for (int n = 0; n < 4; ++n)
        acc[m + 4][n] = __builtin_amdgcn_mfma_f32_16x16x32_bf16(af[m], bn[n], acc[m + 4][n], 0, 0, 0);
    __builtin_amdgcn_s_setprio(0);
    if (pf) { asm volatile("s_waitcnt vmcnt(4)" ::: "memory"); }
    else    { asm volatile("s_waitcnt vmcnt(0)" ::: "memory"); }
    __builtin_amdgcn_s_barrier();

    cur ^= 1;
  }

  const long zoff = SPLIT ? (long)blockIdx.z * M * (long)N : 0;
#pragma unroll
  for (int m = 0; m < 8; ++m)
#pragma unroll
    for (int n = 0; n < 4; ++n) {
      long col = n0 + wc * 64 + n * 16 + l15;
      float bv = SPLIT ? 0.f : bias[col];
      long rowb = m0 + wr * 128 + m * 16 + g * 4;
#pragma unroll
      for (int i = 0; i < 4; ++i) {
        float v = acc[m][n][i] + bv;
        if (RELU) v = fmaxf(v, 0.f);
        Cb[zoff + (rowb + i) * (long)N + col] = f2b(v);
      }
    }
}

// ---------------- merge four bf16 split-K partials + bias -> bf16 ----------------
__global__ __launch_bounds__(256) void merge4_bias(const unsigned short* __restrict__ p,
                                                   const float* __restrict__ bias,
                                                   unsigned short* __restrict__ out) {
  const long PS = 4096L * 1024L;
  long i = ((long)blockIdx.x * 256 + threadIdx.x) * 8;
  int col = (int)(i & 1023);
  float4 b0 = *(const float4*)(bias + col);
  float4 b1 = *(const float4*)(bias + col + 4);
  float acc[8] = {b0.x, b0.y, b0.z, b0.w, b1.x, b1.y, b1.z, b1.w};
#pragma unroll
  for (int sp = 0; sp < 4; ++sp) {
    uint4 u = *(const uint4*)(p + sp * PS + i);
    unsigned r[4] = {u.x, u.y, u.z, u.w};
#pragma unroll
    for (int j = 0; j < 4; ++j) {
      acc[j * 2]     += bitsf(r[j] << 16);
      acc[j * 2 + 1] += bitsf(r[j] & 0xffff0000u);
    }
  }
  unsigned short res[8];
#pragma unroll
  for (int j = 0; j < 8; ++j) res[j] = f2b(acc[j]);
  *(uint4*)(out + i) = *(uint4*)res;
}

// ---------------- flash attention v6: QBLK=256, intra-block split-KV, in-register P ----------------
__global__ __launch_bounds__(512, 2) void attn_kernel(const unsigned short* __restrict__ h,
                                                      unsigned short* __restrict__ o) {
  const int id = blockIdx.y * 8 + blockIdx.x;   // grid (8,32) = 256 blocks
  const int bh = id & 31;
  const int b = bh >> 4, head = bh & 15;
  const int q0 = (id >> 5) * 256;
  const unsigned short* hb = h + (long)b * 2048 * 1024 + head * 64;

  __shared__ unsigned short smem[2 * 19712];

  const int tid = threadIdx.x, wave = tid >> 6, lane = tid & 63;
  const int grp = wave >> 2, wg = wave & 3;
  const int g = lane >> 4, l15 = lane & 15;
  const int vcb = wg * 16;
  unsigned short* Ks0 = smem + grp * 19712;
  unsigned short* VTb = Ks0 + 8192;

  for (int idx = wg * 64 + lane; idx < 16 * 72; idx += 256) {
    unsigned short v = (idx < 72) ? (unsigned short)0x3F80 : (unsigned short)0;
    VTb[64 * 72 + idx] = v;
    VTb[5760 + 64 * 72 + idx] = v;
  }

  const float C1 = 0.18033688011112042f;  // 0.125 * log2(e)

  bf16v8 qf[4][2];
#pragma unroll
  for (int qt = 0; qt < 4; ++qt)
#pragma unroll
    for (int d = 0; d < 2; ++d) {
      bf16v8 q = *(const bf16v8*)(hb + (long)(q0 + wg * 64 + qt * 16 + l15) * 1024 + d * 32 + g * 8);
#pragma unroll
      for (int j = 0; j < 8; ++j) q[j] = (__bf16)((float)q[j] * C1);
      qf[qt][d] = q;
    }

  const int krow = lane >> 3;
  const int kcol = ((lane & 7) ^ (krow & 7)) << 3;

  const int kl = lane;
  const int vpos = ((kl >> 5) << 5) + (((kl & 15) >> 2) << 3) + (((kl >> 4) & 1) << 2) + (kl & 3);

#pragma unroll
  for (int s = 0; s < 2; ++s) {
    int seg = wg * 2 + s;
    gl_lds16(hb + (long)(grp * 64 + seg * 8 + krow) * 1024 + kcol, Ks0 + seg * 512);
  }
  uint4 va0, va1;
  {
    const unsigned short* vg = hb + (long)(grp * 64 + lane) * 1024 + vcb;
    va0 = *(const uint4*)vg;
    va1 = *(const uint4*)(vg + 8);
  }
  {
    unsigned short vv[16];
    *(uint4*)&vv[0] = va0;
    *(uint4*)&vv[8] = va1;
#pragma unroll
    for (int j = 0; j < 16; ++j) VTb[(vcb + j) * 72 + vpos] = vv[j];
  }
  __syncthreads();

  f32x4 accO[4][4] = {};
  f32x4 accL[4] = {};

  int cur = 0;
  for (int t = 0; t < 16; ++t) {
    if (t < 15) {
      const int k0n = ((t + 1) * 2 + grp) * 64;
#pragma unroll
      for (int s = 0; s < 2; ++s) {
        int seg = wg * 2 + s;
        gl_lds16(hb + (long)(k0n + seg * 8 + krow) * 1024 + kcol, Ks0 + (cur ^ 1) * 4096 + seg * 512);
      }
      const unsigned short* vg = hb + (long)(k0n + lane) * 1024 + vcb;
      va0 = *(const uint4*)vg;
      va1 = *(const uint4*)(vg + 8);
    }

    const unsigned short* Kc = Ks0 + cur * 4096;
    f32x4 sf[4][4] = {};
#pragma unroll
    for (int d = 0; d < 2; ++d) {
#pragma unroll
      for (int kt = 0; kt < 4; ++kt) {
        int r = kt * 16 + l15;
        bf16v8 kf = *(const bf16v8*)&Kc[r * 64 + ((((d << 2) + g) ^ (r & 7)) << 3)];
#pragma unroll
        for (int qt = 0; qt < 4; ++qt)
          sf[kt][qt] = __builtin_amdgcn_mfma_f32_16x16x32_bf16(kf, qf[qt][d], sf[kt][qt], 0, 0, 0);
      }
    }

    bf16v8 pa[4][2];
#pragma unroll
    for (int qt = 0; qt < 4; ++qt) {
      float pe[4][4];
#pragma unroll
      for (int kt = 0; kt < 4; ++kt)
#pragma unroll
        for (int i = 0; i < 4; ++i)
          pe[kt][i] = __builtin_amdgcn_exp2f(sf[kt][qt][i]);
#pragma unroll
      for (int i = 0; i < 4; ++i) {
        pa[qt][0][i]     = (__bf16)pe[0][i];
        pa[qt][0][i + 4] = (__bf16)pe[1][i];
        pa[qt][1][i]     = (__bf16)pe[2][i];
        pa[qt][1][i + 4] = (__bf16)pe[3][i];
      }
    }

    const unsigned short* VTc = VTb + cur * 5760;
#pragma unroll
    for (int ks = 0; ks < 2; ++ks) {
      bf16v8 vl = *(const bf16v8*)&VTc[(64 + l15) * 72 + ks * 32 + g * 8];
#pragma unroll
      for (int dt = 0; dt < 4; ++dt) {
        bf16v8 vf = *(const bf16v8*)&VTc[(dt * 16 + l15) * 72 + ks * 32 + g * 8];
#pragma unroll
        for (int qt = 0; qt < 4; ++qt)
          accO[qt][dt] = __builtin_amdgcn_mfma_f32_16x16x32_bf16(pa[qt][ks], vf, accO[qt][dt], 0, 0, 0);
      }
#pragma unroll
      for (int qt = 0; qt < 4; ++qt)
        accL[qt] = __builtin_amdgcn_mfma_f32_16x16x32_bf16(pa[qt][ks], vl, accL[qt], 0, 0, 0);
    }

    if (t < 15) {
      unsigned short vv[16];
      *(uint4*)&vv[0] = va0;
      *(uint4*)&vv[8] = va1;
      unsigned short* VTn = VTb + (cur ^ 1) * 5760;
#pragma unroll
      for (int j = 0; j < 16; ++j) VTn[(vcb + j) * 72 + vpos] = vv[j];
    }
    __syncthreads();
    cur ^= 1;
  }

  float* redO = (float*)smem;
  float* redL = (float*)smem + 16384;
  if (grp == 1) {
#pragma unroll
    for (int qt = 0; qt < 4; ++qt)
#pragma unroll
      for (int i = 0; i < 4; ++i) {
        int r = wg * 64 + qt * 16 + g * 4 + i;
#pragma unroll
        for (int dt = 0; dt < 4; ++dt)
          redO[r * 64 + dt * 16 + l15] = accO[qt][dt][i];
        if (l15 == 0) redL[r] = accL[qt][i];
      }
  }
  __syncthreads();
  if (grp == 0) {
#pragma unroll
    for (int qt = 0; qt < 4; ++qt)
#pragma unroll
      for (int i = 0; i < 4; ++i) {
        int r = wg * 64 + qt * 16 + g * 4 + i;
#pragma unroll
        for (int dt = 0; dt < 4; ++dt)
          accO[qt][dt][i] += redO[r * 64 + dt * 16 + l15];
        accL[qt][i] += redL[r];
      }
#pragma unroll
    for (int qt = 0; qt < 4; ++qt)
#pragma unroll
      for (int i = 0; i < 4; ++i) {
        float linv = 1.f / __shfl(accL[qt][i], lane & 48);
        long row = (long)b * 2048 + q0 + wg * 64 + qt * 16 + g * 4 + i;
#pragma unroll
        for (int dt = 0; dt < 4; ++dt)
          o[row * 1024 + head * 64 + dt * 16 + l15] = f2b(accO[qt][dt][i] * linv);
      }
  }
}

// ---------------- LN1: out = LN(x + att_bf16); writes f32 + bf16 ----------------
__global__ __launch_bounds__(256) void ln1_attb(const float* __restrict__ xa,
                                                const unsigned short* __restrict__ ab,
                                                const float* __restrict__ g,
                                                const float* __restrict__ be,
                                                float* __restrict__ of,
                                                unsigned short* __restrict__ ob) {
  const long base = (long)blockIdx.x * 1024;
  const int t = threadIdx.x;
  float4 va = *(const float4*)(xa + base + t * 4);
  uint2 ub = *(const uint2*)(ab + base + t * 4);
  float v0 = va.x + bitsf(ub.x << 16);
  float v1 = va.y + bitsf(ub.x & 0xffff0000u);
  float v2 = va.z + bitsf(ub.y << 16);
  float v3 = va.w + bitsf(ub.y & 0xffff0000u);
  float s = v0 + v1 + v2 + v3;
  float sq = v0 * v0 + v1 * v1 + v2 * v2 + v3 * v3;
#pragma unroll
  for (int m = 1; m < 64; m <<= 1) { s += __shfl_xor(s, m); sq += __shfl_xor(sq, m); }
  __shared__ float red[8];
  const int wave = t >> 6, lane = t & 63;
  if (lane == 0) { red[wave] = s; red[4 + wave] = sq; }
  __syncthreads();
  s = red[0] + red[1] + red[2] + red[3];
  sq = red[4] + red[5] + red[6] + red[7];
  float mean = s * (1.f / 1024.f);
  float var = fmaxf(sq - s * mean, 0.f) * (1.f / 1023.f);
  float inv = 1.f / (sqrtf(var) + 1e-6f);
  float4 gg = *(const float4*)(g + t * 4);
  float4 bb = *(const float4*)(be + t * 4);
  float y0 = gg.x * ((v0 - mean) * inv) + bb.x;
  float y1 = gg.y * ((v1 - mean) * inv) + bb.y;
  float y2 = gg.z * ((v2 - mean) * inv) + bb.z;
  float y3 = gg.w * ((v3 - mean) * inv) + bb.w;
  *(float4*)(of + base + t * 4) = make_float4(y0, y1, y2, y3);
  ushort4 u = make_ushort4(f2b(y0), f2b(y1), f2b(y2), f2b(y3));
  *(ushort4*)(ob + base + t * 4) = u;
}

// ---------------- LN2: out = LN(x1 + sum_4 zp[s] + b2) ----------------
__global__ __launch_bounds__(256) void ln_add_red4(const float* __restrict__ xa,
                                                   const unsigned short* __restrict__ zp,
                                                   const float* __restrict__ bias,
                                                   const float* __restrict__ g,
                                                   const float* __restrict__ be,
                                                   float* __restrict__ of) {
  const long base = (long)blockIdx.x * 1024;
  const int t = threadIdx.x;
  const long PS = 4096L * 1024L;
  float4 va = *(const float4*)(xa + base + t * 4);
  float4 bz = *(const float4*)(bias + t * 4);
  float v0 = va.x + bz.x, v1 = va.y + bz.y, v2 = va.z + bz.z, v3 = va.w + bz.w;
#pragma unroll
  for (int sp = 0; sp < 4; ++sp) {
    uint2 u = *(const uint2*)(zp + sp * PS + base + t * 4);
    v0 += bitsf(u.x << 16);
    v1 += bitsf(u.x & 0xffff0000u);
    v2 += bitsf(u.y << 16);
    v3 += bitsf(u.y & 0xffff0000u);
  }
  float s = v0 + v1 + v2 + v3;
  float sq = v0 * v0 + v1 * v1 + v2 * v2 + v3 * v3;
#pragma unroll
  for (int m = 1; m < 64; m <<= 1) { s += __shfl_xor(s, m); sq += __shfl_xor(sq, m); }
  __shared__ float red[8];
  const int wave = t >> 6, lane = t & 63;
  if (lane == 0) { red[wave] = s; red[4 + wave] = sq; }
  __syncthreads();
  s = red[0] + red[1] + red[2] + red[3];
  sq = red[4] + red[5] + red[6] + red[7];
  float mean = s * (1.f / 1024.f);
  float var = fmaxf(sq - s * mean, 0.f) * (1.f / 1023.f);
  float inv = 1.f / (sqrtf(var) + 1e-6f);
  float4 gg = *(const float4*)(g + t * 4);
  float4 bb = *(const float4*)(be + t * 4);
  float y0 = gg.x * ((v0 - mean) * inv) + bb.x;
  float y1 = gg.y * ((v1 - mean) * inv) + bb.y;
  float y2 = gg.z * ((v2 - mean) * inv) + bb.z;
  float y3 = gg.w * ((v3 - mean) * inv) + bb.w;
  *(float4*)(of + base + t * 4) = make_float4(y0, y1, y2, y3);
}

extern "C" void kernel_launch(void* const* d_in, const int* in_sizes, int n_in,
                              void* d_out, int out_size, void* d_ws, size_t ws_size,
                              hipStream_t stream) {
  const float* x    = (const float*)d_in[0];
  const float* wq   = (const float*)d_in[1];
  const float* bq   = (const float*)d_in[2];
  const float* ln1a = (const float*)d_in[3];
  const float* ln1b = (const float*)d_in[4];
  const float* ln2a = (const float*)d_in[5];
  const float* ln2b = (const float*)d_in[6];
  const float* w1   = (const float*)d_in[7];
  const float* b1   = (const float*)d_in[8];
  const float* w2   = (const float*)d_in[9];
  const float* b2   = (const float*)d_in[10];
  float* out = (float*)d_out;

  char* ws = (char*)d_ws;
  const size_t MB = 1024 * 1024;
  unsigned short* xb  = (unsigned short*)(ws);            // [0,8)
  unsigned short* wqb = (unsigned short*)(ws + 8 * MB);   // [8,10)
  unsigned short* w1b = (unsigned short*)(ws + 10 * MB);  // [10,18)
  unsigned short* w2b = (unsigned short*)(ws + 18 * MB);  // [18,26)
  unsigned short* qp  = (unsigned short*)(ws + 26 * MB);  // [26,58) QKV partials
  unsigned short* yb  = (unsigned short*)(ws + 26 * MB);  // [26,58) FFN mid (after ln1)
  unsigned short* hb  = (unsigned short*)(ws + 58 * MB);  // [58,66)
  unsigned short* att = (unsigned short*)(ws + 66 * MB);  // [66,74) bf16
  unsigned short* zp  = (unsigned short*)(ws + 58 * MB);  // [58,90) FFN2 partials
  float*          x1f = (float*)(ws + 90 * MB);           // [90,106)
  unsigned short* x1b = (unsigned short*)(ws + 106 * MB); // [106,114)

  // all fp32->bf16 converts in one launch
  cvt_all<<<13312, 256, 0, stream>>>(x, wq, w1, w2, xb, wqb, w1b, w2b);

  // h partials = x @ wq^T (split-K=4), merge + bq -> hb
  gemm256p<0, 1><<<dim3(4, 16, 4), 512, 0, stream>>>(xb, wqb, nullptr, qp,
                                                     4096, 1024, 1024, 256);
  merge4_bias<<<2048, 256, 0, stream>>>(qp, bq, hb);

  // attention (QBLK=256, intra-block split-KV, 512 threads; bf16 out)
  attn_kernel<<<dim3(8, 32), 512, 0, stream>>>(hb, att);

  // x1 = LN(x + att)
  ln1_attb<<<4096, 256, 0, stream>>>(x, att, ln1a, ln1b, x1f, x1b);

  // y = relu(x1 @ w1^T + b1)
  gemm256p<1, 0><<<dim3(16, 16, 1), 512, 0, stream>>>(x1b, w1b, b1, yb,
                                                      4096, 4096, 1024, 1024);

  // z partials = y @ w2^T (split-K=4; b2 added in LN2)
  gemm256p<0, 1><<<dim3(4, 16, 4), 512, 0, stream>>>(yb, w2b, nullptr, zp,
                                                     4096, 1024, 4096, 1024);

  // out = LN(x1 + sum(zp) + b2)
  ln_add_red4<<<4096, 256, 0, stream>>>(x1f, zp, b2, ln2a, ln2b, out);
}

// Round 16
// 174.414 us; speedup vs baseline: 1.0345x; 1.0171x over previous
//
#include <hip/hip_runtime.h>

typedef __bf16 bf16v8 __attribute__((ext_vector_type(8)));
typedef float f32x4 __attribute__((ext_vector_type(4)));

#define AS1 __attribute__((address_space(1)))
#define AS3 __attribute__((address_space(3)))

__device__ __forceinline__ void gl_lds16(const void* g, void* s) {
  __builtin_amdgcn_global_load_lds((const AS1 void*)g, (AS3 void*)s, 16, 0, 0);
}

__device__ __forceinline__ unsigned short f2b(float f) {
  union { float f; unsigned u; } v; v.f = f;
  unsigned r = v.u + 0x7fffu + ((v.u >> 16) & 1u);
  return (unsigned short)(r >> 16);
}

__device__ __forceinline__ float bitsf(unsigned u) {
  union { unsigned u; float f; } v; v.u = u;
  return v.f;
}

// ---------------- fused fp32 -> bf16 convert (x, wq, w1, w2 in one launch) ----------------
__global__ __launch_bounds__(256) void cvt_all(const float* __restrict__ x,
                                               const float* __restrict__ wq,
                                               const float* __restrict__ w1,
                                               const float* __restrict__ w2,
                                               unsigned short* __restrict__ xb,
                                               unsigned short* __restrict__ wqb,
                                               unsigned short* __restrict__ w1b,
                                               unsigned short* __restrict__ w2b) {
  int bid = blockIdx.x;
  const float* in;
  unsigned short* out;
  int base;
  if (bid < 4096)       { in = x;  out = xb;  base = bid; }
  else if (bid < 5120)  { in = wq; out = wqb; base = bid - 4096; }
  else if (bid < 9216)  { in = w1; out = w1b; base = bid - 5120; }
  else                  { in = w2; out = w2b; base = bid - 9216; }
  long i = ((long)base * 256 + threadIdx.x) * 4;
  float4 v = *(const float4*)(in + i);
  ushort4 u = make_ushort4(f2b(v.x), f2b(v.y), f2b(v.z), f2b(v.w));
  *(ushort4*)(out + i) = u;
}

// ============ 256x256 bf16 GEMM, 8 waves, 4-phase counted-vmcnt, even read bursts ============
template <int RELU, int SPLIT>
__global__ __launch_bounds__(512, 2) void gemm256p(const unsigned short* __restrict__ A,
                                                   const unsigned short* __restrict__ B,
                                                   const float* __restrict__ bias,
                                                   unsigned short* __restrict__ Cb,
                                                   int M, int N, int K, int Ks) {
  __shared__ unsigned short As[2][2][8192];  // [buf][kk][256*32] = 64 KB
  __shared__ unsigned short Bs[2][2][8192];  // 64 KB

  const int tid = threadIdx.x;
  const int wave = tid >> 6, lane = tid & 63;
  const int wr = wave >> 2, wc = wave & 3;       // 2 x 4 wave grid
  const int g = lane >> 4, l15 = lane & 15;

  // XCD-aware bijective block swizzle (nwg % 8 == 0 for all our grids)
  const int gx = gridDim.x;
  const int nwg = gx * gridDim.y;
  const int lin = blockIdx.y * gx + blockIdx.x;
  const int cpx = nwg >> 3;
  const int swz = (lin & 7) * cpx + (lin >> 3);
  const long m0 = (long)(swz / gx) * 256;
  const long n0 = (long)(swz % gx) * 256;
  const int kBase = blockIdx.z * Ks;

  // staging: lane covers row seg*16 + (lane>>2), source 16B-chunk (lane&3)^((row>>1)&3)
  const int srow = lane >> 2;
  const int schunk = ((lane & 3) ^ ((lane >> 3) & 3)) * 8;

  auto stA = [&](int buf, int kk, int kb) {
#pragma unroll
    for (int j = 0; j < 2; ++j) {
      const int seg = wave * 2 + j;
      gl_lds16(A + (m0 + seg * 16 + srow) * (long)K + kb + kk * 32 + schunk,
               &As[buf][kk][seg * 512]);
    }
  };
  auto stB = [&](int buf, int kk, int kb) {
#pragma unroll
    for (int j = 0; j < 2; ++j) {
      const int seg = wave * 2 + j;
      gl_lds16(B + (n0 + seg * 16 + srow) * (long)K + kb + kk * 32 + schunk,
               &Bs[buf][kk][seg * 512]);
    }
  };

  // swizzled fragment read column (per-lane constant)
  const int sel = (l15 >> 1) & 3;
  const int colA = (g ^ sel) << 3;

  f32x4 acc[8][4] = {};
  const int nt = Ks >> 6;

  // prologue: stage tile 0 (A-k0, B-k0, A-k1, B-k1); publish [0][0]
  stA(0, 0, kBase); stB(0, 0, kBase); stA(0, 1, kBase); stB(0, 1, kBase);
  asm volatile("s_waitcnt vmcnt(4)" ::: "memory");
  __builtin_amdgcn_s_barrier();

  int cur = 0;
  for (int t = 0; t < nt; ++t) {
    const bool pf = (t + 1 < nt);
    const int kbn = kBase + ((t + 1) << 6);
    bf16v8 af[4], bn[4];

    // ---- P1: reads [cur][0] bn0-3 + af(m0-3) ; stage A(next,0)
#pragma unroll
    for (int n = 0; n < 4; ++n)
      bn[n] = *(const bf16v8*)&Bs[cur][0][(wc * 64 + n * 16 + l15) * 32 + colA];
#pragma unroll
    for (int m = 0; m < 4; ++m)
      af[m] = *(const bf16v8*)&As[cur][0][(wr * 128 + m * 16 + l15) * 32 + colA];
    if (pf) stA(cur ^ 1, 0, kbn);
    __builtin_amdgcn_s_barrier();
    asm volatile("s_waitcnt lgkmcnt(0)" ::: "memory");
    __builtin_amdgcn_s_setprio(1);
#pragma unroll
    for (int m = 0; m < 4; ++m)
#pragma unroll
      for (int n = 0; n < 4; ++n)
        acc[m][n] = __builtin_amdgcn_mfma_f32_16x16x32_bf16(af[m], bn[n], acc[m][n], 0, 0, 0);
    __builtin_amdgcn_s_setprio(0);
    __builtin_amdgcn_s_barrier();

    // ---- P2: reads [cur][0] af(m4-7) ; stage B(next,0) ; publish [cur][1]
#pragma unroll
    for (int m = 0; m < 4; ++m)
      af[m] = *(const bf16v8*)&As[cur][0][(wr * 128 + (m + 4) * 16 + l15) * 32 + colA];
    if (pf) stB(cur ^ 1, 0, kbn);
    __builtin_amdgcn_s_barrier();
    asm volatile("s_waitcnt lgkmcnt(0)" ::: "memory");
    __builtin_amdgcn_s_setprio(1);
#pragma unroll
    for (int m = 0; m < 4; ++m)
#pragma unroll
      for (int n = 0; n < 4; ++n)
        acc[m + 4][n] = __builtin_amdgcn_mfma_f32_16x16x32_bf16(af[m], bn[n], acc[m + 4][n], 0, 0, 0);
    __builtin_amdgcn_s_setprio(0);
    if (pf) { asm volatile("s_waitcnt vmcnt(4)" ::: "memory"); }
    else    { asm volatile("s_waitcnt vmcnt(0)" ::: "memory"); }
    __builtin_amdgcn_s_barrier();

    // ---- P3: reads [cur][1] bn0-3 + af(m0-3) ; stage A(next,1)
#pragma unroll
    for (int n = 0; n < 4; ++n)
      bn[n] = *(const bf16v8*)&Bs[cur][1][(wc * 64 + n * 16 + l15) * 32 + colA];
#pragma unroll
    for (int m = 0; m < 4; ++m)
      af[m] = *(const bf16v8*)&As[cur][1][(wr * 128 + m * 16 + l15) * 32 + colA];
    if (pf) stA(cur ^ 1, 1, kbn);
    __builtin_amdgcn_s_barrier();
    asm volatile("s_waitcnt lgkmcnt(0)" ::: "memory");
    __builtin_amdgcn_s_setprio(1);
#pragma unroll
    for (int m = 0; m < 4; ++m)
#pragma unroll
      for (int n = 0; n < 4; ++n)
        acc[m][n] = __builtin_amdgcn_mfma_f32_16x16x32_bf16(af[m], bn[n], acc[m][n], 0, 0, 0);
    __builtin_amdgcn_s_setprio(0);
    __builtin_amdgcn_s_barrier();

    // ---- P4: reads [cur][1] af(m4-7) ; stage B(next,1) ; publish [next][0]
#pragma unroll
    for (int m = 0; m < 4; ++m)
      af[m] = *(const bf16v8*)&As[cur][1][(wr * 128 + (m + 4) * 16 + l15) * 32 + colA];
    if (pf) stB(cur ^ 1, 1, kbn);
    __builtin_amdgcn_s_barrier();
    asm volatile("s_waitcnt lgkmcnt(0)" ::: "memory");
    __builtin_amdgcn_s_setprio(1);
#pragma unroll
    for (int m = 0; m < 4; ++m)
#pragma unroll
      for (int n = 0; n < 4; ++n)
        acc[m + 4][n] = __builtin_amdgcn_mfma_f32_16x16x32_bf16(af[m], bn[n], acc[m + 4][n], 0, 0, 0);
    __builtin_amdgcn_s_setprio(0);
    if (pf) { asm volatile("s_waitcnt vmcnt(4)" ::: "memory"); }
    else    { asm volatile("s_waitcnt vmcnt(0)" ::: "memory"); }
    __builtin_amdgcn_s_barrier();

    cur ^= 1;
  }

  const long zoff = SPLIT ? (long)blockIdx.z * M * (long)N : 0;
#pragma unroll
  for (int m = 0; m < 8; ++m)
#pragma unroll
    for (int n = 0; n < 4; ++n) {
      long col = n0 + wc * 64 + n * 16 + l15;
      float bv = SPLIT ? 0.f : bias[col];
      long rowb = m0 + wr * 128 + m * 16 + g * 4;
#pragma unroll
      for (int i = 0; i < 4; ++i) {
        float v = acc[m][n][i] + bv;
        if (RELU) v = fmaxf(v, 0.f);
        Cb[zoff + (rowb + i) * (long)N + col] = f2b(v);
      }
    }
}

// ---------------- merge four bf16 split-K partials + bias -> bf16 ----------------
__global__ __launch_bounds__(256) void merge4_bias(const unsigned short* __restrict__ p,
                                                   const float* __restrict__ bias,
                                                   unsigned short* __restrict__ out) {
  const long PS = 4096L * 1024L;
  long i = ((long)blockIdx.x * 256 + threadIdx.x) * 8;
  int col = (int)(i & 1023);
  float4 b0 = *(const float4*)(bias + col);
  float4 b1 = *(const float4*)(bias + col + 4);
  float acc[8] = {b0.x, b0.y, b0.z, b0.w, b1.x, b1.y, b1.z, b1.w};
#pragma unroll
  for (int sp = 0; sp < 4; ++sp) {
    uint4 u = *(const uint4*)(p + sp * PS + i);
    unsigned r[4] = {u.x, u.y, u.z, u.w};
#pragma unroll
    for (int j = 0; j < 4; ++j) {
      acc[j * 2]     += bitsf(r[j] << 16);
      acc[j * 2 + 1] += bitsf(r[j] & 0xffff0000u);
    }
  }
  unsigned short res[8];
#pragma unroll
  for (int j = 0; j < 8; ++j) res[j] = f2b(acc[j]);
  *(uint4*)(out + i) = *(uint4*)res;
}

// ---------------- flash attention v6: QBLK=256, intra-block split-KV, in-register P ----------------
__global__ __launch_bounds__(512, 2) void attn_kernel(const unsigned short* __restrict__ h,
                                                      unsigned short* __restrict__ o) {
  const int id = blockIdx.y * 8 + blockIdx.x;   // grid (8,32) = 256 blocks
  const int bh = id & 31;
  const int b = bh >> 4, head = bh & 15;
  const int q0 = (id >> 5) * 256;
  const unsigned short* hb = h + (long)b * 2048 * 1024 + head * 64;

  __shared__ unsigned short smem[2 * 19712];

  const int tid = threadIdx.x, wave = tid >> 6, lane = tid & 63;
  const int grp = wave >> 2, wg = wave & 3;
  const int g = lane >> 4, l15 = lane & 15;
  const int vcb = wg * 16;
  unsigned short* Ks0 = smem + grp * 19712;
  unsigned short* VTb = Ks0 + 8192;

  for (int idx = wg * 64 + lane; idx < 16 * 72; idx += 256) {
    unsigned short v = (idx < 72) ? (unsigned short)0x3F80 : (unsigned short)0;
    VTb[64 * 72 + idx] = v;
    VTb[5760 + 64 * 72 + idx] = v;
  }

  const float C1 = 0.18033688011112042f;  // 0.125 * log2(e)

  bf16v8 qf[4][2];
#pragma unroll
  for (int qt = 0; qt < 4; ++qt)
#pragma unroll
    for (int d = 0; d < 2; ++d) {
      bf16v8 q = *(const bf16v8*)(hb + (long)(q0 + wg * 64 + qt * 16 + l15) * 1024 + d * 32 + g * 8);
#pragma unroll
      for (int j = 0; j < 8; ++j) q[j] = (__bf16)((float)q[j] * C1);
      qf[qt][d] = q;
    }

  const int krow = lane >> 3;
  const int kcol = ((lane & 7) ^ (krow & 7)) << 3;

  const int kl = lane;
  const int vpos = ((kl >> 5) << 5) + (((kl & 15) >> 2) << 3) + (((kl >> 4) & 1) << 2) + (kl & 3);

#pragma unroll
  for (int s = 0; s < 2; ++s) {
    int seg = wg * 2 + s;
    gl_lds16(hb + (long)(grp * 64 + seg * 8 + krow) * 1024 + kcol, Ks0 + seg * 512);
  }
  uint4 va0, va1;
  {
    const unsigned short* vg = hb + (long)(grp * 64 + lane) * 1024 + vcb;
    va0 = *(const uint4*)vg;
    va1 = *(const uint4*)(vg + 8);
  }
  {
    unsigned short vv[16];
    *(uint4*)&vv[0] = va0;
    *(uint4*)&vv[8] = va1;
#pragma unroll
    for (int j = 0; j < 16; ++j) VTb[(vcb + j) * 72 + vpos] = vv[j];
  }
  __syncthreads();

  f32x4 accO[4][4] = {};
  f32x4 accL[4] = {};

  int cur = 0;
  for (int t = 0; t < 16; ++t) {
    if (t < 15) {
      const int k0n = ((t + 1) * 2 + grp) * 64;
#pragma unroll
      for (int s = 0; s < 2; ++s) {
        int seg = wg * 2 + s;
        gl_lds16(hb + (long)(k0n + seg * 8 + krow) * 1024 + kcol, Ks0 + (cur ^ 1) * 4096 + seg * 512);
      }
      const unsigned short* vg = hb + (long)(k0n + lane) * 1024 + vcb;
      va0 = *(const uint4*)vg;
      va1 = *(const uint4*)(vg + 8);
    }

    const unsigned short* Kc = Ks0 + cur * 4096;
    f32x4 sf[4][4] = {};
#pragma unroll
    for (int d = 0; d < 2; ++d) {
#pragma unroll
      for (int kt = 0; kt < 4; ++kt) {
        int r = kt * 16 + l15;
        bf16v8 kf = *(const bf16v8*)&Kc[r * 64 + ((((d << 2) + g) ^ (r & 7)) << 3)];
#pragma unroll
        for (int qt = 0; qt < 4; ++qt)
          sf[kt][qt] = __builtin_amdgcn_mfma_f32_16x16x32_bf16(kf, qf[qt][d], sf[kt][qt], 0, 0, 0);
      }
    }

    bf16v8 pa[4][2];
#pragma unroll
    for (int qt = 0; qt < 4; ++qt) {
      float pe[4][4];
#pragma unroll
      for (int kt = 0; kt < 4; ++kt)
#pragma unroll
        for (int i = 0; i < 4; ++i)
          pe[kt][i] = __builtin_amdgcn_exp2f(sf[kt][qt][i]);
#pragma unroll
      for (int i = 0; i < 4; ++i) {
        pa[qt][0][i]     = (__bf16)pe[0][i];
        pa[qt][0][i + 4] = (__bf16)pe[1][i];
        pa[qt][1][i]     = (__bf16)pe[2][i];
        pa[qt][1][i + 4] = (__bf16)pe[3][i];
      }
    }

    const unsigned short* VTc = VTb + cur * 5760;
#pragma unroll
    for (int ks = 0; ks < 2; ++ks) {
      bf16v8 vl = *(const bf16v8*)&VTc[(64 + l15) * 72 + ks * 32 + g * 8];
#pragma unroll
      for (int dt = 0; dt < 4; ++dt) {
        bf16v8 vf = *(const bf16v8*)&VTc[(dt * 16 + l15) * 72 + ks * 32 + g * 8];
#pragma unroll
        for (int qt = 0; qt < 4; ++qt)
          accO[qt][dt] = __builtin_amdgcn_mfma_f32_16x16x32_bf16(pa[qt][ks], vf, accO[qt][dt], 0, 0, 0);
      }
#pragma unroll
      for (int qt = 0; qt < 4; ++qt)
        accL[qt] = __builtin_amdgcn_mfma_f32_16x16x32_bf16(pa[qt][ks], vl, accL[qt], 0, 0, 0);
    }

    if (t < 15) {
      unsigned short vv[16];
      *(uint4*)&vv[0] = va0;
      *(uint4*)&vv[8] = va1;
      unsigned short* VTn = VTb + (cur ^ 1) * 5760;
#pragma unroll
      for (int j = 0; j < 16; ++j) VTn[(vcb + j) * 72 + vpos] = vv[j];
    }
    __syncthreads();
    cur ^= 1;
  }

  float* redO = (float*)smem;
  float* redL = (float*)smem + 16384;
  if (grp == 1) {
#pragma unroll
    for (int qt = 0; qt < 4; ++qt)
#pragma unroll
      for (int i = 0; i < 4; ++i) {
        int r = wg * 64 + qt * 16 + g * 4 + i;
#pragma unroll
        for (int dt = 0; dt < 4; ++dt)
          redO[r * 64 + dt * 16 + l15] = accO[qt][dt][i];
        if (l15 == 0) redL[r] = accL[qt][i];
      }
  }
  __syncthreads();
  if (grp == 0) {
#pragma unroll
    for (int qt = 0; qt < 4; ++qt)
#pragma unroll
      for (int i = 0; i < 4; ++i) {
        int r = wg * 64 + qt * 16 + g * 4 + i;
#pragma unroll
        for (int dt = 0; dt < 4; ++dt)
          accO[qt][dt][i] += redO[r * 64 + dt * 16 + l15];
        accL[qt][i] += redL[r];
      }
#pragma unroll
    for (int qt = 0; qt < 4; ++qt)
#pragma unroll
      for (int i = 0; i < 4; ++i) {
        float linv = 1.f / __shfl(accL[qt][i], lane & 48);
        long row = (long)b * 2048 + q0 + wg * 64 + qt * 16 + g * 4 + i;
#pragma unroll
        for (int dt = 0; dt < 4; ++dt)
          o[row * 1024 + head * 64 + dt * 16 + l15] = f2b(accO[qt][dt][i] * linv);
      }
  }
}

// ---------------- LN1: x1 = LN(x + att_bf16); writes bf16 only ----------------
__global__ __launch_bounds__(256) void ln1_attb(const float* __restrict__ xa,
                                                const unsigned short* __restrict__ ab,
                                                const float* __restrict__ g,
                                                const float* __restrict__ be,
                                                unsigned short* __restrict__ ob) {
  const long base = (long)blockIdx.x * 1024;
  const int t = threadIdx.x;
  float4 va = *(const float4*)(xa + base + t * 4);
  uint2 ub = *(const uint2*)(ab + base + t * 4);
  float v0 = va.x + bitsf(ub.x << 16);
  float v1 = va.y + bitsf(ub.x & 0xffff0000u);
  float v2 = va.z + bitsf(ub.y << 16);
  float v3 = va.w + bitsf(ub.y & 0xffff0000u);
  float s = v0 + v1 + v2 + v3;
  float sq = v0 * v0 + v1 * v1 + v2 * v2 + v3 * v3;
#pragma unroll
  for (int m = 1; m < 64; m <<= 1) { s += __shfl_xor(s, m); sq += __shfl_xor(sq, m); }
  __shared__ float red[8];
  const int wave = t >> 6, lane = t & 63;
  if (lane == 0) { red[wave] = s; red[4 + wave] = sq; }
  __syncthreads();
  s = red[0] + red[1] + red[2] + red[3];
  sq = red[4] + red[5] + red[6] + red[7];
  float mean = s * (1.f / 1024.f);
  float var = fmaxf(sq - s * mean, 0.f) * (1.f / 1023.f);
  float inv = 1.f / (sqrtf(var) + 1e-6f);
  float4 gg = *(const float4*)(g + t * 4);
  float4 bb = *(const float4*)(be + t * 4);
  float y0 = gg.x * ((v0 - mean) * inv) + bb.x;
  float y1 = gg.y * ((v1 - mean) * inv) + bb.y;
  float y2 = gg.z * ((v2 - mean) * inv) + bb.z;
  float y3 = gg.w * ((v3 - mean) * inv) + bb.w;
  ushort4 u = make_ushort4(f2b(y0), f2b(y1), f2b(y2), f2b(y3));
  *(ushort4*)(ob + base + t * 4) = u;
}

// ---------------- LN2: out = LN(x1b + sum_4 zp[s] + b2) ----------------
__global__ __launch_bounds__(256) void ln_add_red4(const unsigned short* __restrict__ x1b,
                                                   const unsigned short* __restrict__ zp,
                                                   const float* __restrict__ bias,
                                                   const float* __restrict__ g,
                                                   const float* __restrict__ be,
                                                   float* __restrict__ of) {
  const long base = (long)blockIdx.x * 1024;
  const int t = threadIdx.x;
  const long PS = 4096L * 1024L;
  uint2 ux = *(const uint2*)(x1b + base + t * 4);
  float4 bz = *(const float4*)(bias + t * 4);
  float v0 = bitsf(ux.x << 16)         + bz.x;
  float v1 = bitsf(ux.x & 0xffff0000u) + bz.y;
  float v2 = bitsf(ux.y << 16)         + bz.z;
  float v3 = bitsf(ux.y & 0xffff0000u) + bz.w;
#pragma unroll
  for (int sp = 0; sp < 4; ++sp) {
    uint2 u = *(const uint2*)(zp + sp * PS + base + t * 4);
    v0 += bitsf(u.x << 16);
    v1 += bitsf(u.x & 0xffff0000u);
    v2 += bitsf(u.y << 16);
    v3 += bitsf(u.y & 0xffff0000u);
  }
  float s = v0 + v1 + v2 + v3;
  float sq = v0 * v0 + v1 * v1 + v2 * v2 + v3 * v3;
#pragma unroll
  for (int m = 1; m < 64; m <<= 1) { s += __shfl_xor(s, m); sq += __shfl_xor(sq, m); }
  __shared__ float red[8];
  const int wave = t >> 6, lane = t & 63;
  if (lane == 0) { red[wave] = s; red[4 + wave] = sq; }
  __syncthreads();
  s = red[0] + red[1] + red[2] + red[3];
  sq = red[4] + red[5] + red[6] + red[7];
  float mean = s * (1.f / 1024.f);
  float var = fmaxf(sq - s * mean, 0.f) * (1.f / 1023.f);
  float inv = 1.f / (sqrtf(var) + 1e-6f);
  float4 gg = *(const float4*)(g + t * 4);
  float4 bb = *(const float4*)(be + t * 4);
  float y0 = gg.x * ((v0 - mean) * inv) + bb.x;
  float y1 = gg.y * ((v1 - mean) * inv) + bb.y;
  float y2 = gg.z * ((v2 - mean) * inv) + bb.z;
  float y3 = gg.w * ((v3 - mean) * inv) + bb.w;
  *(float4*)(of + base + t * 4) = make_float4(y0, y1, y2, y3);
}

extern "C" void kernel_launch(void* const* d_in, const int* in_sizes, int n_in,
                              void* d_out, int out_size, void* d_ws, size_t ws_size,
                              hipStream_t stream) {
  const float* x    = (const float*)d_in[0];
  const float* wq   = (const float*)d_in[1];
  const float* bq   = (const float*)d_in[2];
  const float* ln1a = (const float*)d_in[3];
  const float* ln1b = (const float*)d_in[4];
  const float* ln2a = (const float*)d_in[5];
  const float* ln2b = (const float*)d_in[6];
  const float* w1   = (const float*)d_in[7];
  const float* b1   = (const float*)d_in[8];
  const float* w2   = (const float*)d_in[9];
  const float* b2   = (const float*)d_in[10];
  float* out = (float*)d_out;

  char* ws = (char*)d_ws;
  const size_t MB = 1024 * 1024;
  unsigned short* xb  = (unsigned short*)(ws);            // [0,8)
  unsigned short* wqb = (unsigned short*)(ws + 8 * MB);   // [8,10)
  unsigned short* w1b = (unsigned short*)(ws + 10 * MB);  // [10,18)
  unsigned short* w2b = (unsigned short*)(ws + 18 * MB);  // [18,26)
  unsigned short* qp  = (unsigned short*)(ws + 26 * MB);  // [26,58) QKV partials
  unsigned short* yb  = (unsigned short*)(ws + 26 * MB);  // [26,58) FFN mid (after ln1)
  unsigned short* hb  = (unsigned short*)(ws + 58 * MB);  // [58,66)
  unsigned short* att = (unsigned short*)(ws + 66 * MB);  // [66,74) bf16
  unsigned short* zp  = (unsigned short*)(ws + 58 * MB);  // [58,90) FFN2 partials
  unsigned short* x1b = (unsigned short*)(ws + 106 * MB); // [106,114)

  // all fp32->bf16 converts in one launch
  cvt_all<<<13312, 256, 0, stream>>>(x, wq, w1, w2, xb, wqb, w1b, w2b);

  // h partials = x @ wq^T (split-K=4), merge + bq -> hb
  gemm256p<0, 1><<<dim3(4, 16, 4), 512, 0, stream>>>(xb, wqb, nullptr, qp,
                                                     4096, 1024, 1024, 256);
  merge4_bias<<<2048, 256, 0, stream>>>(qp, bq, hb);

  // attention (QBLK=256, intra-block split-KV, 512 threads; bf16 out)
  attn_kernel<<<dim3(8, 32), 512, 0, stream>>>(hb, att);

  // x1 = LN(x + att)  (bf16 only)
  ln1_attb<<<4096, 256, 0, stream>>>(x, att, ln1a, ln1b, x1b);

  // y = relu(x1 @ w1^T + b1)
  gemm256p<1, 0><<<dim3(16, 16, 1), 512, 0, stream>>>(x1b, w1b, b1, yb,
                                                      4096, 4096, 1024, 1024);

  // z partials = y @ w2^T (split-K=4; b2 added in LN2)
  gemm256p<0, 1><<<dim3(4, 16, 4), 512, 0, stream>>>(yb, w2b, nullptr, zp,
                                                     4096, 1024, 4096, 1024);

  // out = LN(x1 + sum(zp) + b2)
  ln_add_red4<<<4096, 256, 0, stream>>>(x1b, zp, b2, ln2a, ln2b, out);
}